// Round 1
// baseline (352.121 us; speedup 1.0000x reference)
//
#include <hip/hip_runtime.h>

#define NF    100
#define TILE  128
#define BLOCK 256
#define MAXF4 13   // ceil(TILE*25 / BLOCK) = ceil(3200/256)

// Kernel A: M_re[k,a] = sum_ij P_re[i,j]*A_real[k,i,j,a] - P_im[i,j]*A_imag[k,i,j,a]
// Stored interleaved: M2[a] = (M_re[0,a], M_re[1,a])
__global__ __launch_bounds__(128) void compute_M_kernel(
    const float* __restrict__ A_real, const float* __restrict__ A_imag,
    const float* __restrict__ psi_real, const float* __restrict__ psi_imag,
    float2* __restrict__ M2) {
  int a = threadIdx.x;
  if (a >= NF) return;
  float pr[10], pi[10];
#pragma unroll
  for (int i = 0; i < 10; ++i) { pr[i] = psi_real[i]; pi[i] = psi_imag[i]; }
  float m0 = 0.f, m1 = 0.f;
#pragma unroll
  for (int i = 0; i < 10; ++i) {
#pragma unroll
    for (int j = 0; j < 10; ++j) {
      float pre = pr[i] * pr[j] + pi[i] * pi[j];
      float pim = pr[i] * pi[j] - pi[i] * pr[j];
      int off = (i * 10 + j) * NF + a;          // k=0
      m0 = fmaf(pre, A_real[off], m0);
      m0 = fmaf(-pim, A_imag[off], m0);
      m1 = fmaf(pre, A_real[off + 10000], m1);  // k=1: +10*10*100
      m1 = fmaf(-pim, A_imag[off + 10000], m1);
    }
  }
  M2[a] = make_float2(m0, m1);
}

// Kernel B: out[t,:] = x[t,:] @ M^T.  128-row tile staged in LDS, 2 threads/row.
__global__ __launch_bounds__(BLOCK) void out_kernel(
    const float4* __restrict__ x4, const float2* __restrict__ M2,
    float2* __restrict__ out, int batch) {
  __shared__ float4 xs4[TILE * 25];  // 51.2 KB, unpadded (b128-friendly)
  __shared__ float2 ms[NF];          // 0.8 KB
  const int tid = threadIdx.x;
  const int t0 = blockIdx.x * TILE;
  int rows = batch - t0;
  if (rows > TILE) rows = TILE;
  const int n4 = rows * 25;

  if (tid < NF) ms[tid] = M2[tid];

  // Stage: 13 independent float4 loads per thread (one latency, not 13),
  // then aligned ds_write_b128 stores.
  const float4* src = x4 + (long)t0 * 25;
  float4 v[MAXF4];
#pragma unroll
  for (int u = 0; u < MAXF4; ++u) {
    int f = tid + u * BLOCK;
    if (f < n4) v[u] = src[f];
  }
#pragma unroll
  for (int u = 0; u < MAXF4; ++u) {
    int f = tid + u * BLOCK;
    if (f < n4) xs4[f] = v[u];
  }
  __syncthreads();

  // Compute: thread pair (2r, 2r+1) handles row r; each half dots 50 elems.
  const int r = tid >> 1;
  const int h = tid & 1;
  const float2* xr = (const float2*)(xs4 + r * 25) + h * 25;  // 8B-aligned
  const float2* mr = ms + h * 50;
  float a0 = 0.f, a1 = 0.f;
#pragma unroll
  for (int i = 0; i < 25; ++i) {
    float2 xv = xr[i];
    float2 mA = mr[2 * i];
    float2 mB = mr[2 * i + 1];
    a0 = fmaf(xv.x, mA.x, a0);
    a1 = fmaf(xv.x, mA.y, a1);
    a0 = fmaf(xv.y, mB.x, a0);
    a1 = fmaf(xv.y, mB.y, a1);
  }
  // Combine the two halves of each row (lanes differ only in bit 0).
  a0 += __shfl_xor(a0, 1);
  a1 += __shfl_xor(a1, 1);
  if (h == 0 && r < rows) out[t0 + r] = make_float2(a0, a1);
}

extern "C" void kernel_launch(void* const* d_in, const int* in_sizes, int n_in,
                              void* d_out, int out_size, void* d_ws, size_t ws_size,
                              hipStream_t stream) {
  const float* x  = (const float*)d_in[0];
  const float* Ar = (const float*)d_in[1];
  const float* Ai = (const float*)d_in[2];
  const float* pr = (const float*)d_in[3];
  const float* pi = (const float*)d_in[4];
  const int batch = in_sizes[0] / NF;

  float2* M2 = (float2*)d_ws;  // 800 B of workspace
  compute_M_kernel<<<1, 128, 0, stream>>>(Ar, Ai, pr, pi, M2);

  const int nblocks = (batch + TILE - 1) / TILE;
  out_kernel<<<nblocks, BLOCK, 0, stream>>>(
      (const float4*)x, (const float2*)M2, (float2*)d_out, batch);
}

// Round 2
// 283.972 us; speedup vs baseline: 1.2400x; 1.2400x over previous
//
#include <hip/hip_runtime.h>
#include <stdint.h>

#define NF     100
#define TILE   64
#define BLOCK  256
#define F4T    (TILE * 25)                 // 1600 float4 per tile (25.6 KB)
#define NLD    ((F4T + BLOCK - 1) / BLOCK) // 7 staging issues per thread
#define GRID   768                         // 3 blocks/CU * 256 CUs (LDS-limited)

// ---------------------------------------------------------------------------
// Kernel A: M_re[k,a] = sum_ij P_re[i,j]*A_real[k,i,j,a] - P_im[i,j]*A_imag[k,i,j,a]
// Stored interleaved: M2[a] = (M_re[0,a], M_re[1,a])
__global__ __launch_bounds__(128) void compute_M_kernel(
    const float* __restrict__ A_real, const float* __restrict__ A_imag,
    const float* __restrict__ psi_real, const float* __restrict__ psi_imag,
    float2* __restrict__ M2) {
  int a = threadIdx.x;
  if (a >= NF) return;
  float pr[10], pi[10];
#pragma unroll
  for (int i = 0; i < 10; ++i) { pr[i] = psi_real[i]; pi[i] = psi_imag[i]; }
  float m0 = 0.f, m1 = 0.f;
#pragma unroll
  for (int i = 0; i < 10; ++i) {
#pragma unroll
    for (int j = 0; j < 10; ++j) {
      float pre = pr[i] * pr[j] + pi[i] * pi[j];
      float pim = pr[i] * pi[j] - pi[i] * pr[j];
      int off = (i * 10 + j) * NF + a;          // k=0
      m0 = fmaf(pre, A_real[off], m0);
      m0 = fmaf(-pim, A_imag[off], m0);
      m1 = fmaf(pre, A_real[off + 10000], m1);  // k=1
      m1 = fmaf(-pim, A_imag[off + 10000], m1);
    }
  }
  M2[a] = make_float2(m0, m1);
}

// ---------------------------------------------------------------------------
// Async global->LDS staging of one 64-row tile of x.
// LDS dest pattern is wave-uniform base + lane*16 (required by global_load_lds):
// f = u*256 + wave*64 + lane, dst offset = f*16B.  Tail guard cuts at wave
// granularity for full tiles; partial-wave exec masks are also fine.
__device__ __forceinline__ void stage_tile(const float4* __restrict__ x4,
                                           float4* dst, int tile, int batch,
                                           int tid) {
  const int t0 = tile * TILE;
  int rows = batch - t0;
  if (rows > TILE) rows = TILE;
  const int n4 = rows * 25;
  const float4* src = x4 + (size_t)t0 * 25;
#pragma unroll
  for (int u = 0; u < NLD; ++u) {
    int f = u * BLOCK + tid;
    if (f < n4) {
      __builtin_amdgcn_global_load_lds(
          (const __attribute__((address_space(1))) void*)(src + f),
          (__attribute__((address_space(3))) void*)(dst + f), 16, 0, 0);
    }
  }
}

// ---------------------------------------------------------------------------
// Kernel B: persistent blocks, grid-stride over tiles, double-buffered LDS.
// Per iteration: [barrier = vmcnt drain of buf ready] -> issue next tile's
// async loads into other buf -> compute current buf -> swap.  Loads are
// always in flight; block never retires mid-stream.
__global__ __launch_bounds__(BLOCK) void out_kernel(
    const float4* __restrict__ x4, const float4* __restrict__ M4,
    float2* __restrict__ out, int batch, int ntiles) {
  __shared__ float4 xs[2][F4T];   // 2 x 25.6 KB
  __shared__ float4 ms[NF / 2];   // M as (m0[2j], m1[2j], m0[2j+1], m1[2j+1])

  const int tid = threadIdx.x;
  if (tid < NF / 2) ms[tid] = M4[tid];

  const int r = tid >> 1;         // row within tile (2 threads/row)
  const int h = tid & 1;          // which 50-feature half
  const int stride = gridDim.x;

  int tile = blockIdx.x;
  if (tile >= ntiles) return;

  stage_tile(x4, &xs[0][0], tile, batch, tid);  // prologue -> buf 0
  int buf = 0;

  for (; tile < ntiles; tile += stride) {
    __syncthreads();  // drains vmcnt: xs[buf] loaded; ms ready; prev compute done

    const int nxt = tile + stride;
    if (nxt < ntiles) stage_tile(x4, &xs[buf ^ 1][0], nxt, batch, tid);

    const int t0 = tile * TILE;
    int rows = batch - t0;
    if (rows > TILE) rows = TILE;

    const float2* xr = (const float2*)(&xs[buf][0] + (size_t)r * 25) + h * 25;
    const float4* mr = ms + h * 25;
    float a0 = 0.f, a1 = 0.f;
#pragma unroll
    for (int i = 0; i < 25; ++i) {
      float2 xv = xr[i];
      float4 m = mr[i];              // features h*50+2i, h*50+2i+1 (broadcast)
      a0 = fmaf(xv.x, m.x, a0);
      a1 = fmaf(xv.x, m.y, a1);
      a0 = fmaf(xv.y, m.z, a0);
      a1 = fmaf(xv.y, m.w, a1);
    }
    a0 += __shfl_xor(a0, 1);
    a1 += __shfl_xor(a1, 1);
    if (h == 0 && r < rows) out[t0 + r] = make_float2(a0, a1);

    buf ^= 1;
  }
}

// ---------------------------------------------------------------------------
extern "C" void kernel_launch(void* const* d_in, const int* in_sizes, int n_in,
                              void* d_out, int out_size, void* d_ws, size_t ws_size,
                              hipStream_t stream) {
  const float* x  = (const float*)d_in[0];
  const float* Ar = (const float*)d_in[1];
  const float* Ai = (const float*)d_in[2];
  const float* pr = (const float*)d_in[3];
  const float* pi = (const float*)d_in[4];
  const int batch = in_sizes[0] / NF;

  float2* M2 = (float2*)d_ws;  // 800 B of workspace
  compute_M_kernel<<<1, 128, 0, stream>>>(Ar, Ai, pr, pi, M2);

  const int ntiles = (batch + TILE - 1) / TILE;
  const int grid = ntiles < GRID ? ntiles : GRID;
  out_kernel<<<grid, BLOCK, 0, stream>>>(
      (const float4*)x, (const float4*)M2, (float2*)d_out, batch, ntiles);
}